// Round 4
// baseline (686.298 us; speedup 1.0000x reference)
//
#include <hip/hip_runtime.h>

typedef _Float16 f16;
typedef f16   f16x8 __attribute__((ext_vector_type(8)));
typedef float f32x4 __attribute__((ext_vector_type(4)));

#define NF 256      // features
#define NH 64       // hidden dim
#define NL 3        // hidden-to-hidden layers
#define WROWS 32    // batch rows per wave (2 subtiles of 16)
#define NWAVE 4
#define MT (WROWS * NWAVE)   // 128 rows per block
#define NTHR (NWAVE * 64)    // 256
#define WFRAG (NH * NH)      // 4096 f16 per plane per (l,f)

// f32-unit swizzled index into the h plane [MT][NH]; XOR flips col bits 2-4
// (16B units): keeps f32x4 chunks contiguous, spreads stride-256B rows.
__device__ __forceinline__ int hswz(int r, int c) {
    return r * NH + (c ^ ((r & 7) << 2));
}

// ---- prepass: split Wh into f16 hi/lo fragment planes, laid out so the
// ---- main kernel's per-lane f16x8 load is fully coalesced (1KB/instr).
__global__ __launch_bounds__(256) void presplit_w(
    const float* __restrict__ Wh, f16* __restrict__ wsHi, f16* __restrict__ wsLo)
{
    __shared__ float wld[NH * NH];
    const int lf = blockIdx.x;            // l*NF + f
    const int t  = threadIdx.x;
    const float* __restrict__ src = Wh + (size_t)lf * WFRAG;
#pragma unroll
    for (int i = 0; i < 4; ++i)
        *(f32x4*)&wld[(i * 256 + t) * 4] = *(const f32x4*)&src[(i * 256 + t) * 4];
    __syncthreads();
#pragma unroll
    for (int g2 = 0; g2 < 2; ++g2) {
        const int g  = g2 * 256 + t;      // g = nt*128 + ks*64 + ln
        const int ln = g & 63, ks = (g >> 6) & 1, nt = g >> 7;
        const int cl = ln & 15, gr = ln >> 4;
        f16x8 hi, lo;
#pragma unroll
        for (int jj = 0; jj < 8; ++jj) {
            const int k = ks * 32 + gr * 8 + jj;   // input-hidden index
            const int n = nt * 16 + cl;            // output-hidden index
            float v = wld[k * NH + n];
            f16 h = (f16)v;
            hi[jj] = h;
            lo[jj] = (f16)(v - (float)h);
        }
        const size_t dst = ((size_t)lf * 512 + g) * 8;
        *(f16x8*)&wsHi[dst] = hi;
        *(f16x8*)&wsLo[dst] = lo;
    }
}

template <bool PRE>
__global__ __launch_bounds__(NTHR, 4) void permlp_v4(
    const float* __restrict__ x,
    const float* __restrict__ W1,
    const float* __restrict__ b1,
    const float* __restrict__ Wh,
    const float* __restrict__ bh,
    const float* __restrict__ Wo,
    const float* __restrict__ bo,
    const f16* __restrict__ wsHi,
    const f16* __restrict__ wsLo,
    float* __restrict__ out)
{
    __shared__ float hbuf[MT * NH];   // 32 KB

    const int f   = blockIdx.x;
    const int tid = threadIdx.x;
    const int wv  = tid >> 6;
    const int ln  = tid & 63;
    const int cl  = ln & 15;
    const int gr  = ln >> 4;
    const int lr0 = wv * WROWS;
    const int gb0 = blockIdx.y * MT + lr0;

    // ---- layer 1: 2 lanes per row (32 cols each), wave-private rows ----
    {
        const int r    = ln >> 1;
        const int half = ln & 1;
        const float xv = x[(size_t)(gb0 + r) * NF + f];
        const float* __restrict__ w1 = W1 + f * NH + half * 32;  // uniform base
        const float* __restrict__ bb = b1 + f * NH + half * 32;
        const int rr = lr0 + r;
#pragma unroll
        for (int c4 = 0; c4 < 8; ++c4) {
            f32x4 v;
#pragma unroll
            for (int j = 0; j < 4; ++j)
                v[j] = fmaxf(fmaf(xv, w1[c4 * 4 + j], bb[c4 * 4 + j]), 0.f);
            *(f32x4*)&hbuf[hswz(rr, half * 32 + c4 * 4)] = v;
        }
    }
    // NO barriers: every wave touches only its own 32 rows.

    // ---- hidden layers ----
    for (int l = 0; l < NL; ++l) {
        f16x8 bhi[4][2], blo[4][2];   // W fragments in registers
        if constexpr (PRE) {
            const f16* __restrict__ baseH = wsHi + (size_t)(l * NF + f) * 512 * 8;
            const f16* __restrict__ baseL = wsLo + (size_t)(l * NF + f) * 512 * 8;
#pragma unroll
            for (int nt = 0; nt < 4; ++nt)
#pragma unroll
                for (int ks = 0; ks < 2; ++ks) {
                    const size_t off = (size_t)((nt * 2 + ks) * 64 + ln) * 8;
                    bhi[nt][ks] = *(const f16x8*)&baseH[off];
                    blo[nt][ks] = *(const f16x8*)&baseL[off];
                }
        } else {
            const float* __restrict__ Wl = Wh + (size_t)(l * NF + f) * WFRAG;
#pragma unroll
            for (int nt = 0; nt < 4; ++nt)
#pragma unroll
                for (int ks = 0; ks < 2; ++ks) {
                    const int n  = nt * 16 + cl;
                    const int kb = ks * 32 + gr * 8;
                    const float* __restrict__ col = Wl + (size_t)kb * NH + n;
                    f16x8 hi8, lo8;
#pragma unroll
                    for (int j = 0; j < 8; ++j) {
                        float v = col[(size_t)j * NH];
                        f16 h = (f16)v;
                        hi8[j] = h;
                        lo8[j] = (f16)(v - (float)h);
                    }
                    bhi[nt][ks] = hi8;
                    blo[nt][ks] = lo8;
                }
        }
        float biasl[4];
#pragma unroll
        for (int nt = 0; nt < 4; ++nt)
            biasl[nt] = bh[(size_t)(l * NF + f) * NH + nt * 16 + cl];

#pragma unroll
        for (int st = 0; st < 2; ++st) {
            const int m0 = lr0 + st * 16;
            const int m  = m0 + cl;
            f16x8 ahi[2], alo[2];
#pragma unroll
            for (int ks = 0; ks < 2; ++ks) {
                const int k0 = ks * 32 + gr * 8;
                f32x4 a0 = *(const f32x4*)&hbuf[hswz(m, k0)];
                f32x4 a1 = *(const f32x4*)&hbuf[hswz(m, k0 + 4)];
                f16x8 hi8, lo8;
#pragma unroll
                for (int j = 0; j < 4; ++j) {
                    f16 h = (f16)a0[j];
                    hi8[j] = h; lo8[j] = (f16)(a0[j] - (float)h);
                }
#pragma unroll
                for (int j = 0; j < 4; ++j) {
                    f16 h = (f16)a1[j];
                    hi8[4 + j] = h; lo8[4 + j] = (f16)(a1[j] - (float)h);
                }
                ahi[ks] = hi8; alo[ks] = lo8;
            }
            f32x4 acc[4];
#pragma unroll
            for (int nt = 0; nt < 4; ++nt) {
                f32x4 z{0.f, 0.f, 0.f, 0.f};
                acc[nt] = z;
            }
#pragma unroll
            for (int nt = 0; nt < 4; ++nt)
#pragma unroll
                for (int ks = 0; ks < 2; ++ks) {
                    acc[nt] = __builtin_amdgcn_mfma_f32_16x16x32_f16(ahi[ks], bhi[nt][ks], acc[nt], 0, 0, 0);
                    acc[nt] = __builtin_amdgcn_mfma_f32_16x16x32_f16(alo[ks], bhi[nt][ks], acc[nt], 0, 0, 0);
                    acc[nt] = __builtin_amdgcn_mfma_f32_16x16x32_f16(ahi[ks], blo[nt][ks], acc[nt], 0, 0, 0);
                }
#pragma unroll
            for (int nt = 0; nt < 4; ++nt) {
                const float bb = biasl[nt];
#pragma unroll
                for (int i = 0; i < 4; ++i)
                    hbuf[hswz(m0 + gr * 4 + i, nt * 16 + cl)] =
                        fmaxf(acc[nt][i] + bb, 0.f);
            }
        }
    }

    // ---- output layer as MFMA with broadcast-Wo B operand ----
    {
        f16x8 wohi[2], wolo[2];
#pragma unroll
        for (int ks = 0; ks < 2; ++ks) {
            const int kb = ks * 32 + gr * 8;
            f16x8 hi8, lo8;
#pragma unroll
            for (int j = 0; j < 8; ++j) {
                float v = Wo[f * NH + kb + j];
                f16 h = (f16)v;
                hi8[j] = h;
                lo8[j] = (f16)(v - (float)h);
            }
            wohi[ks] = hi8; wolo[ks] = lo8;
        }
        const float bof = bo[f];
#pragma unroll
        for (int st = 0; st < 2; ++st) {
            const int m0 = lr0 + st * 16;
            const int m  = m0 + cl;
            f16x8 ahi[2], alo[2];
#pragma unroll
            for (int ks = 0; ks < 2; ++ks) {
                const int k0 = ks * 32 + gr * 8;
                f32x4 a0 = *(const f32x4*)&hbuf[hswz(m, k0)];
                f32x4 a1 = *(const f32x4*)&hbuf[hswz(m, k0 + 4)];
                f16x8 hi8, lo8;
#pragma unroll
                for (int j = 0; j < 4; ++j) {
                    f16 h = (f16)a0[j];
                    hi8[j] = h; lo8[j] = (f16)(a0[j] - (float)h);
                }
#pragma unroll
                for (int j = 0; j < 4; ++j) {
                    f16 h = (f16)a1[j];
                    hi8[4 + j] = h; lo8[4 + j] = (f16)(a1[j] - (float)h);
                }
                ahi[ks] = hi8; alo[ks] = lo8;
            }
            f32x4 a2{0.f, 0.f, 0.f, 0.f};
#pragma unroll
            for (int ks = 0; ks < 2; ++ks) {
                a2 = __builtin_amdgcn_mfma_f32_16x16x32_f16(ahi[ks], wohi[ks], a2, 0, 0, 0);
                a2 = __builtin_amdgcn_mfma_f32_16x16x32_f16(alo[ks], wohi[ks], a2, 0, 0, 0);
                a2 = __builtin_amdgcn_mfma_f32_16x16x32_f16(ahi[ks], wolo[ks], a2, 0, 0, 0);
            }
            if (cl == 0) {
#pragma unroll
                for (int i = 0; i < 4; ++i)
                    atomicAdd(&out[gb0 + st * 16 + gr * 4 + i], a2[i] + bof);
            }
        }
    }
}

extern "C" void kernel_launch(void* const* d_in, const int* in_sizes, int n_in,
                              void* d_out, int out_size, void* d_ws, size_t ws_size,
                              hipStream_t stream)
{
    const float* x  = (const float*)d_in[0];
    const float* W1 = (const float*)d_in[1];
    const float* b1 = (const float*)d_in[2];
    const float* Wh = (const float*)d_in[3];
    const float* bh = (const float*)d_in[4];
    const float* Wo = (const float*)d_in[5];
    const float* bo = (const float*)d_in[6];
    float* out = (float*)d_out;

    const int B = in_sizes[0] / NF;   // 16384

    hipMemsetAsync(out, 0, (size_t)out_size * sizeof(float), stream);

    const size_t planeElems = (size_t)NL * NF * WFRAG;          // 3.15M f16
    const size_t needW      = planeElems * 2 * sizeof(f16);     // ~12.6 MB
    dim3 grid(NF, B / MT);

    if (ws_size >= needW) {
        f16* wsHi = (f16*)d_ws;
        f16* wsLo = wsHi + planeElems;
        presplit_w<<<NL * NF, 256, 0, stream>>>(Wh, wsHi, wsLo);
        permlp_v4<true><<<grid, dim3(NTHR), 0, stream>>>(
            x, W1, b1, Wh, bh, Wo, bo, wsHi, wsLo, out);
    } else {
        permlp_v4<false><<<grid, dim3(NTHR), 0, stream>>>(
            x, W1, b1, Wh, bh, Wo, bo, nullptr, nullptr, out);
    }
}

// Round 5
// 416.626 us; speedup vs baseline: 1.6473x; 1.6473x over previous
//
#include <hip/hip_runtime.h>

typedef _Float16 f16;
typedef f16   f16x8 __attribute__((ext_vector_type(8)));
typedef float f32x4 __attribute__((ext_vector_type(4)));

#define NF 256      // features
#define NH 64       // hidden dim
#define NL 3        // hidden-to-hidden layers
#define WROWS 32    // batch rows per wave (2 subtiles of 16)
#define NWAVE 4
#define MT (WROWS * NWAVE)   // 128 rows per block
#define NTHR (NWAVE * 64)    // 256
#define WFRAG (NH * NH)

// f32-unit swizzled index into the h plane [MT][NH]; XOR flips col bits 2-4
// (16B units): keeps f32x4 chunks contiguous, spreads stride-256B rows.
__device__ __forceinline__ int hswz(int r, int c) {
    return r * NH + (c ^ ((r & 7) << 2));
}

// ---- prepass: split Wh into f16 hi/lo fragment planes, laid out so the
// ---- main kernel's per-lane f16x8 load is fully coalesced (1KB/instr).
__global__ __launch_bounds__(256) void presplit_w(
    const float* __restrict__ Wh, f16* __restrict__ wsHi, f16* __restrict__ wsLo)
{
    __shared__ float wld[NH * NH];
    const int lf = blockIdx.x;            // l*NF + f
    const int t  = threadIdx.x;
    const float* __restrict__ src = Wh + (size_t)lf * WFRAG;
#pragma unroll
    for (int i = 0; i < 4; ++i)
        *(f32x4*)&wld[(i * 256 + t) * 4] = *(const f32x4*)&src[(i * 256 + t) * 4];
    __syncthreads();
#pragma unroll
    for (int g2 = 0; g2 < 2; ++g2) {
        const int g  = g2 * 256 + t;      // g = (nt*2+ks)*64 + ln
        const int ln = g & 63, ks = (g >> 6) & 1, nt = g >> 7;
        const int cl = ln & 15, gr = ln >> 4;
        f16x8 hi, lo;
#pragma unroll
        for (int jj = 0; jj < 8; ++jj) {
            const int k = ks * 32 + gr * 8 + jj;   // input-hidden index
            const int n = nt * 16 + cl;            // output-hidden index
            float v = wld[k * NH + n];
            f16 h = (f16)v;
            hi[jj] = h;
            lo[jj] = (f16)(v - (float)h);
        }
        const size_t dst = ((size_t)lf * 512 + g) * 8;
        *(f16x8*)&wsHi[dst] = hi;
        *(f16x8*)&wsLo[dst] = lo;
    }
}

template <bool PRE>
__global__ __launch_bounds__(NTHR, 4) void permlp_v5(
    const float* __restrict__ x,
    const float* __restrict__ W1,
    const float* __restrict__ b1,
    const float* __restrict__ Wh,
    const float* __restrict__ bh,
    const float* __restrict__ Wo,
    const float* __restrict__ bo,
    const f16* __restrict__ wsHi,
    const f16* __restrict__ wsLo,
    float* __restrict__ out,
    int nby)
{
    __shared__ float hbuf[MT * NH];   // 32 KB -> 4 blocks/CU

    // XCD-chunked bijective swizzle (nwg % 8 == 0): XCD i gets a contiguous
    // f-chunk with `by` varying fastest -> resident W per XCD ~1 slice,
    // x cache lines XCD-private -> L2-resident working set.
    const int nwg  = NF * nby;
    const int q    = nwg >> 3;
    const int bid  = blockIdx.x;
    const int wgid = (bid & 7) * q + (bid >> 3);
    const int f    = wgid / nby;
    const int by   = wgid - f * nby;

    const int tid = threadIdx.x;
    const int wv  = tid >> 6;
    const int ln  = tid & 63;
    const int cl  = ln & 15;
    const int gr  = ln >> 4;
    const int lr0 = wv * WROWS;
    const int gb0 = by * MT + lr0;

    // ---- hoist all epilogue constants ----
    float biasv[NL][4];
#pragma unroll
    for (int l = 0; l < NL; ++l)
#pragma unroll
        for (int nt = 0; nt < 4; ++nt)
            biasv[l][nt] = bh[(size_t)(l * NF + f) * NH + nt * 16 + cl];

    // ---- layer 1: 2 lanes per row (32 cols each), wave-private rows ----
    {
        const int r    = ln >> 1;
        const int half = ln & 1;
        const float xv = x[(size_t)(gb0 + r) * NF + f];
        const float* __restrict__ w1 = W1 + f * NH + half * 32;  // uniform base
        const float* __restrict__ bb = b1 + f * NH + half * 32;
        const int rr = lr0 + r;
#pragma unroll
        for (int c4 = 0; c4 < 8; ++c4) {
            f32x4 v;
#pragma unroll
            for (int j = 0; j < 4; ++j)
                v[j] = fmaxf(fmaf(xv, w1[c4 * 4 + j], bb[c4 * 4 + j]), 0.f);
            *(f32x4*)&hbuf[hswz(rr, half * 32 + c4 * 4)] = v;
        }
    }
    // NO barriers: every wave touches only its own 32 rows.

    // ---- hidden layers: A-fragments first, W streamed through 8 VGPRs ----
    for (int l = 0; l < NL; ++l) {
        f16x8 ahi[2][2], alo[2][2];   // [st][ks]
#pragma unroll
        for (int st = 0; st < 2; ++st) {
            const int m = lr0 + st * 16 + cl;
#pragma unroll
            for (int ks = 0; ks < 2; ++ks) {
                const int k0 = ks * 32 + gr * 8;
                f32x4 a0 = *(const f32x4*)&hbuf[hswz(m, k0)];
                f32x4 a1 = *(const f32x4*)&hbuf[hswz(m, k0 + 4)];
                f16x8 hi8, lo8;
#pragma unroll
                for (int j = 0; j < 4; ++j) {
                    f16 h = (f16)a0[j];
                    hi8[j] = h; lo8[j] = (f16)(a0[j] - (float)h);
                }
#pragma unroll
                for (int j = 0; j < 4; ++j) {
                    f16 h = (f16)a1[j];
                    hi8[4 + j] = h; lo8[4 + j] = (f16)(a1[j] - (float)h);
                }
                ahi[st][ks] = hi8; alo[st][ks] = lo8;
            }
        }

        f32x4 acc[2][4];
#pragma unroll
        for (int st = 0; st < 2; ++st)
#pragma unroll
            for (int nt = 0; nt < 4; ++nt) {
                f32x4 z{0.f, 0.f, 0.f, 0.f};
                acc[st][nt] = z;
            }

        const f16* __restrict__ baseH = PRE ? wsHi + (size_t)(l * NF + f) * 4096 : nullptr;
        const f16* __restrict__ baseL = PRE ? wsLo + (size_t)(l * NF + f) * 4096 : nullptr;
        const float* __restrict__ Wl  = Wh + (size_t)(l * NF + f) * WFRAG;

#pragma unroll
        for (int nt = 0; nt < 4; ++nt)
#pragma unroll
            for (int ks = 0; ks < 2; ++ks) {
                f16x8 bhi8, blo8;
                if constexpr (PRE) {
                    const size_t off = (size_t)((nt * 2 + ks) * 64 + ln) * 8;
                    bhi8 = *(const f16x8*)&baseH[off];
                    blo8 = *(const f16x8*)&baseL[off];
                } else {
                    const int n  = nt * 16 + cl;
                    const int kb = ks * 32 + gr * 8;
                    const float* __restrict__ col = Wl + (size_t)kb * NH + n;
#pragma unroll
                    for (int j = 0; j < 8; ++j) {
                        float v = col[(size_t)j * NH];
                        f16 h = (f16)v;
                        bhi8[j] = h;
                        blo8[j] = (f16)(v - (float)h);
                    }
                }
#pragma unroll
                for (int st = 0; st < 2; ++st) {
                    acc[st][nt] = __builtin_amdgcn_mfma_f32_16x16x32_f16(ahi[st][ks], bhi8, acc[st][nt], 0, 0, 0);
                    acc[st][nt] = __builtin_amdgcn_mfma_f32_16x16x32_f16(alo[st][ks], bhi8, acc[st][nt], 0, 0, 0);
                    acc[st][nt] = __builtin_amdgcn_mfma_f32_16x16x32_f16(ahi[st][ks], blo8, acc[st][nt], 0, 0, 0);
                }
            }

        // epilogue: store relu(acc + bias) back as f32 (post-relu h)
#pragma unroll
        for (int st = 0; st < 2; ++st) {
            const int m0 = lr0 + st * 16;
#pragma unroll
            for (int nt = 0; nt < 4; ++nt) {
                const float bb = biasv[l][nt];
#pragma unroll
                for (int i = 0; i < 4; ++i)
                    hbuf[hswz(m0 + gr * 4 + i, nt * 16 + cl)] =
                        fmaxf(acc[st][nt][i] + bb, 0.f);
            }
        }
    }

    // ---- output layer as MFMA with broadcast-Wo B operand ----
    {
        f16x8 wohi[2], wolo[2];
#pragma unroll
        for (int ks = 0; ks < 2; ++ks) {
            const int kb = ks * 32 + gr * 8;
            f16x8 hi8, lo8;
#pragma unroll
            for (int j = 0; j < 8; ++j) {
                float v = Wo[f * NH + kb + j];
                f16 h = (f16)v;
                hi8[j] = h;
                lo8[j] = (f16)(v - (float)h);
            }
            wohi[ks] = hi8; wolo[ks] = lo8;
        }
        const float bof = bo[f];
#pragma unroll
        for (int st = 0; st < 2; ++st) {
            const int m0 = lr0 + st * 16;
            const int m  = m0 + cl;
            f16x8 ahi[2], alo[2];
#pragma unroll
            for (int ks = 0; ks < 2; ++ks) {
                const int k0 = ks * 32 + gr * 8;
                f32x4 a0 = *(const f32x4*)&hbuf[hswz(m, k0)];
                f32x4 a1 = *(const f32x4*)&hbuf[hswz(m, k0 + 4)];
                f16x8 hi8, lo8;
#pragma unroll
                for (int j = 0; j < 4; ++j) {
                    f16 h = (f16)a0[j];
                    hi8[j] = h; lo8[j] = (f16)(a0[j] - (float)h);
                }
#pragma unroll
                for (int j = 0; j < 4; ++j) {
                    f16 h = (f16)a1[j];
                    hi8[4 + j] = h; lo8[4 + j] = (f16)(a1[j] - (float)h);
                }
                ahi[ks] = hi8; alo[ks] = lo8;
            }
            f32x4 a2{0.f, 0.f, 0.f, 0.f};
#pragma unroll
            for (int ks = 0; ks < 2; ++ks) {
                a2 = __builtin_amdgcn_mfma_f32_16x16x32_f16(ahi[ks], wohi[ks], a2, 0, 0, 0);
                a2 = __builtin_amdgcn_mfma_f32_16x16x32_f16(alo[ks], wohi[ks], a2, 0, 0, 0);
                a2 = __builtin_amdgcn_mfma_f32_16x16x32_f16(ahi[ks], wolo[ks], a2, 0, 0, 0);
            }
            if (cl == 0) {
#pragma unroll
                for (int i = 0; i < 4; ++i)
                    atomicAdd(&out[gb0 + st * 16 + gr * 4 + i], a2[i] + bof);
            }
        }
    }
}

extern "C" void kernel_launch(void* const* d_in, const int* in_sizes, int n_in,
                              void* d_out, int out_size, void* d_ws, size_t ws_size,
                              hipStream_t stream)
{
    const float* x  = (const float*)d_in[0];
    const float* W1 = (const float*)d_in[1];
    const float* b1 = (const float*)d_in[2];
    const float* Wh = (const float*)d_in[3];
    const float* bh = (const float*)d_in[4];
    const float* Wo = (const float*)d_in[5];
    const float* bo = (const float*)d_in[6];
    float* out = (float*)d_out;

    const int B   = in_sizes[0] / NF;   // 16384
    const int nby = B / MT;             // 128

    hipMemsetAsync(out, 0, (size_t)out_size * sizeof(float), stream);

    const size_t planeElems = (size_t)NL * NF * WFRAG;          // 3.15M f16
    const size_t needW      = planeElems * 2 * sizeof(f16);     // ~12.6 MB
    dim3 grid(NF * nby);

    if (ws_size >= needW) {
        f16* wsHi = (f16*)d_ws;
        f16* wsLo = wsHi + planeElems;
        presplit_w<<<NL * NF, 256, 0, stream>>>(Wh, wsHi, wsLo);
        permlp_v5<true><<<grid, dim3(NTHR), 0, stream>>>(
            x, W1, b1, Wh, bh, Wo, bo, wsHi, wsLo, out, nby);
    } else {
        permlp_v5<false><<<grid, dim3(NTHR), 0, stream>>>(
            x, W1, b1, Wh, bh, Wo, bo, nullptr, nullptr, out, nby);
    }
}